// Round 1
// baseline (565.355 us; speedup 1.0000x reference)
//
#include <hip/hip_runtime.h>
#include <stdint.h>

// Problem: B=4, S=2048, d_in=d_out=1024. fp32 in/out, f16 MFMA internally.
// Pipeline: cvt(x,W) -> QKV gemm -> transpose V -> per batch:
//   scores gemm (f32, causal block-skip) -> column stats (softmax over axis=1!)
//   -> P = exp(s-m_j)/Z_j (f16) -> PV gemm -> out f32.

typedef __attribute__((ext_vector_type(8))) _Float16 half8;
typedef __attribute__((ext_vector_type(4))) float f32x4;

__device__ __forceinline__ ushort f2h(float f) {
  _Float16 h = (_Float16)f;
  union { _Float16 h; ushort u; } v; v.h = h; return v.u;
}

// ---------------- convert / transpose kernels ----------------
__global__ void k_cvt_x(const float* __restrict__ x, ushort* __restrict__ xh) {
  int i = (blockIdx.x * 256 + threadIdx.x) * 4;
  float4 v = *(const float4*)(x + i);
  ushort4 o;
  o.x = f2h(v.x); o.y = f2h(v.y); o.z = f2h(v.z); o.w = f2h(v.w);
  *(ushort4*)(xh + i) = o;
}

// W (1024x1024 f32, [d][e]) -> Wt f16 [e][d]; 3 matrices stacked (Wq,Wk,Wv)
__global__ void k_cvt_w(const float* __restrict__ Wq, const float* __restrict__ Wk,
                        const float* __restrict__ Wv, ushort* __restrict__ Wt) {
  __shared__ ushort tile[32][33];
  const float* W = blockIdx.z == 0 ? Wq : blockIdx.z == 1 ? Wk : Wv;
  int e0 = blockIdx.x * 32, d0 = blockIdx.y * 32;
  for (int r = threadIdx.y; r < 32; r += 8)
    tile[r][threadIdx.x] = f2h(W[(size_t)(d0 + r) * 1024 + e0 + threadIdx.x]);
  __syncthreads();
  ushort* out = Wt + (size_t)blockIdx.z * 1024 * 1024;
  for (int r = threadIdx.y; r < 32; r += 8)
    out[(size_t)(e0 + r) * 1024 + d0 + threadIdx.x] = tile[threadIdx.x][r];
}

// V f16 [b*2048+j][e] -> Vt [b][e][j]
__global__ void k_tr_v(const ushort* __restrict__ V, ushort* __restrict__ Vt) {
  __shared__ ushort tile[32][33];
  int b = blockIdx.z;
  int e0 = blockIdx.x * 32, j0 = blockIdx.y * 32;
  const ushort* src = V + (size_t)b * 2048 * 1024;
  for (int r = threadIdx.y; r < 32; r += 8)
    tile[r][threadIdx.x] = src[(size_t)(j0 + r) * 1024 + e0 + threadIdx.x];
  __syncthreads();
  ushort* dst = Vt + (size_t)b * 1024 * 2048;
  for (int r = threadIdx.y; r < 32; r += 8)
    dst[(size_t)(e0 + r) * 2048 + j0 + threadIdx.x] = tile[threadIdx.x][r];
}

// ---------------- GEMM core (m97-style, 128x128xBK64, 4 waves) ----------------
__device__ __forceinline__ void gload_lds16(const ushort* g, ushort* l) {
  __builtin_amdgcn_global_load_lds(
      (const __attribute__((address_space(1))) void*)g,
      (__attribute__((address_space(3))) void*)l, 16, 0, 0);
}

// EPI: 0 = QKV split (f16 x3), 1 = scores (f32, scale+causal, skip bn>bm), 2 = PV (f32)
template <int EPI>
__global__ __launch_bounds__(256)
void k_gemm(const ushort* __restrict__ A, const ushort* __restrict__ Bt,
            int K, int lda, int ldb, void* o0, void* o1, void* o2) {
  int bm = blockIdx.y, bn = blockIdx.x;
  if (EPI == 1 && bn > bm) return;   // fully-masked causal tile
  __shared__ __align__(16) ushort As[128 * 64];
  __shared__ __align__(16) ushort Bs[128 * 64];
  int t = threadIdx.x;
  int lane = t & 63, wave = t >> 6;
  int wm = (wave >> 1) * 64, wn = (wave & 1) * 64;
  f32x4 acc[4][4] = {};

  int r0 = t >> 3, c0 = (t & 7) * 8;
  const int nk = K >> 6;
  for (int kt = 0; kt < nk; ++kt) {
    const ushort* ga = A + (size_t)(bm * 128) * lda + kt * 64;
    const ushort* gb = Bt + (size_t)(bn * 128) * ldb + kt * 64;
#pragma unroll
    for (int it = 0; it < 4; ++it) {
      int r = it * 32 + r0;
      gload_lds16(ga + (size_t)r * lda + c0, &As[(it * 256 + t) * 8]);
      gload_lds16(gb + (size_t)r * ldb + c0, &Bs[(it * 256 + t) * 8]);
    }
    __syncthreads();
#pragma unroll
    for (int kk = 0; kk < 2; ++kk) {
      half8 af[4], bf[4];
#pragma unroll
      for (int i = 0; i < 4; ++i) {
        af[i] = *(const half8*)&As[(wm + i * 16 + (lane & 15)) * 64 + kk * 32 + (lane >> 4) * 8];
        bf[i] = *(const half8*)&Bs[(wn + i * 16 + (lane & 15)) * 64 + kk * 32 + (lane >> 4) * 8];
      }
#pragma unroll
      for (int i = 0; i < 4; ++i)
#pragma unroll
        for (int j = 0; j < 4; ++j)
          acc[i][j] = __builtin_amdgcn_mfma_f32_16x16x32_f16(af[i], bf[j], acc[i][j], 0, 0, 0);
    }
    __syncthreads();
  }

  int row0 = bm * 128 + wm + ((lane >> 4) << 2);
  int col0 = bn * 128 + wn + (lane & 15);
  if (EPI == 0) {
    ushort* q = (ushort*)o0; ushort* kk_ = (ushort*)o1; ushort* v = (ushort*)o2;
#pragma unroll
    for (int i = 0; i < 4; ++i)
#pragma unroll
      for (int j = 0; j < 4; ++j) {
        int col = col0 + j * 16;
        ushort* dst = col < 1024 ? q : col < 2048 ? kk_ : v;
        int cn = col & 1023;
#pragma unroll
        for (int r = 0; r < 4; ++r)
          dst[(size_t)(row0 + i * 16 + r) * 1024 + cn] = f2h(acc[i][j][r]);
      }
  } else if (EPI == 1) {
    float* sc = (float*)o0;
#pragma unroll
    for (int i = 0; i < 4; ++i)
#pragma unroll
      for (int j = 0; j < 4; ++j) {
        int col = col0 + j * 16;
#pragma unroll
        for (int r = 0; r < 4; ++r) {
          int row = row0 + i * 16 + r;
          float vv = acc[i][j][r] * 0.03125f;   // 1/sqrt(1024)
          if (col > row) vv = -1e30f;           // causal (j > i)
          sc[(size_t)row * 2048 + col] = vv;
        }
      }
  } else {
    float* o = (float*)o0;
#pragma unroll
    for (int i = 0; i < 4; ++i)
#pragma unroll
      for (int j = 0; j < 4; ++j) {
        int col = col0 + j * 16;
#pragma unroll
        for (int r = 0; r < 4; ++r)
          o[(size_t)(row0 + i * 16 + r) * 1024 + col] = acc[i][j][r];
      }
  }
}

// ---------------- column softmax stats (softmax over i, per column j) ----------------
__global__ void k_stats1(const float* __restrict__ Sc, float* __restrict__ pm,
                         float* __restrict__ pz) {
  int j = blockIdx.x * 256 + threadIdx.x;
  int i0 = blockIdx.y * 128;
  float m = -1e30f, z = 0.f;
  for (int i = i0; i < i0 + 128; ++i) {
    float s = Sc[(size_t)i * 2048 + j];
    if (i >= j) {                 // only unmasked rows
      float nm = fmaxf(m, s);
      z = z * __expf(m - nm) + __expf(s - nm);
      m = nm;
    }
  }
  pm[blockIdx.y * 2048 + j] = m;
  pz[blockIdx.y * 2048 + j] = z;
}

__global__ void k_stats2(const float* __restrict__ pm, const float* __restrict__ pz,
                         float* __restrict__ cm, float* __restrict__ cz) {
  int j = blockIdx.x * 256 + threadIdx.x;
  float m = -1e30f;
#pragma unroll
  for (int c = 0; c < 16; ++c) m = fmaxf(m, pm[c * 2048 + j]);
  float z = 0.f;
#pragma unroll
  for (int c = 0; c < 16; ++c) {
    float zz = pz[c * 2048 + j];
    if (zz > 0.f) z += zz * __expf(pm[c * 2048 + j] - m);
  }
  cm[j] = m;
  cz[j] = 1.0f / z;
}

// P[i][j] = (j<=i) ? exp(s - m_j)/Z_j : 0   (f16)
__global__ void k_pmat(const float* __restrict__ Sc, const float* __restrict__ cm,
                       const float* __restrict__ cz, ushort* __restrict__ P) {
  int t = blockIdx.x * 256 + threadIdx.x;
  int i = t >> 9;
  int j0 = (t & 511) << 2;
  float4 s = *(const float4*)&Sc[(size_t)i * 2048 + j0];
  float4 m4 = *(const float4*)&cm[j0];
  float4 z4 = *(const float4*)&cz[j0];
  ushort4 o;
  o.x = (j0 + 0 <= i) ? f2h(__expf(s.x - m4.x) * z4.x) : (ushort)0;
  o.y = (j0 + 1 <= i) ? f2h(__expf(s.y - m4.y) * z4.y) : (ushort)0;
  o.z = (j0 + 2 <= i) ? f2h(__expf(s.z - m4.z) * z4.z) : (ushort)0;
  o.w = (j0 + 3 <= i) ? f2h(__expf(s.w - m4.w) * z4.w) : (ushort)0;
  *(ushort4*)&P[(size_t)i * 2048 + j0] = o;
}

// ---------------- host ----------------
extern "C" void kernel_launch(void* const* d_in, const int* in_sizes, int n_in,
                              void* d_out, int out_size, void* d_ws, size_t ws_size,
                              hipStream_t stream) {
  const float* x  = (const float*)d_in[0];
  const float* Wq = (const float*)d_in[1];
  const float* Wk = (const float*)d_in[2];
  const float* Wv = (const float*)d_in[3];
  float* out = (float*)d_out;
  char* ws = (char*)d_ws;

  // ws layout (bytes) — total ~115.7 MB
  ushort* xh = (ushort*)(ws);                 // 8192*1024*2   = 16,777,216
  ushort* Wt = (ushort*)(ws + 16777216);      // 3072*1024*2   =  6,291,456
  ushort* Qh = (ushort*)(ws + 23068672);      // 16,777,216
  ushort* Kh = (ushort*)(ws + 39845888);      // 16,777,216
  ushort* Vh = (ushort*)(ws + 56623104);      // 16,777,216
  ushort* Vt = (ushort*)(ws + 73400320);      // 16,777,216
  float*  Sc = (float*) (ws + 90177536);      // 2048*2048*4   = 16,777,216 (per-batch reuse)
  ushort* P  = (ushort*)(ws + 106954752);     // 2048*2048*2   =  8,388,608 (per-batch reuse)
  float*  pm = (float*) (ws + 115343360);     // 16*2048*4     =    131,072
  float*  pz = (float*) (ws + 115474432);     //    131,072
  float*  cm = (float*) (ws + 115605504);     //      8,192
  float*  cz = (float*) (ws + 115613696);     //      8,192

  k_cvt_x<<<8192, 256, 0, stream>>>(x, xh);
  k_cvt_w<<<dim3(32, 32, 3), dim3(32, 8), 0, stream>>>(Wq, Wk, Wv, Wt);
  // fused QKV projection: A = xh [8192x1024], Bt = Wt [3072x1024]
  k_gemm<0><<<dim3(24, 64), 256, 0, stream>>>(xh, Wt, 1024, 1024, 1024, Qh, Kh, Vh);
  k_tr_v<<<dim3(32, 64, 4), dim3(32, 8), 0, stream>>>(Vh, Vt);

  for (int b = 0; b < 4; ++b) {
    const ushort* Qb  = Qh + (size_t)b * 2048 * 1024;
    const ushort* Kb  = Kh + (size_t)b * 2048 * 1024;
    const ushort* Vtb = Vt + (size_t)b * 1024 * 2048;
    // scores: C[i][j] = Q_i . K_j  (Bt = K row-major works as B^T)
    k_gemm<1><<<dim3(16, 16), 256, 0, stream>>>(Qb, Kb, 1024, 1024, 1024, Sc, nullptr, nullptr);
    k_stats1<<<dim3(8, 16), 256, 0, stream>>>(Sc, pm, pz);
    k_stats2<<<8, 256, 0, stream>>>(pm, pz, cm, cz);
    k_pmat<<<4096, 256, 0, stream>>>(Sc, cm, cz, P);
    // context: A = P [2048x2048], Bt = Vt[b] [1024 e][2048 j]
    k_gemm<2><<<dim3(8, 16), 256, 0, stream>>>(P, Vtb, 2048, 2048, 2048,
                                               out + (size_t)b * 2048 * 1024, nullptr, nullptr);
  }
}

// Round 2
// 267.990 us; speedup vs baseline: 2.1096x; 2.1096x over previous
//
#include <hip/hip_runtime.h>
#include <stdint.h>

// B=4, S=2048, d=1024. fp32 in/out, f16 MFMA internally.
// Pipeline: cvt(x,W) -> QKV gemm -> transpose V -> (batched over z):
//   scores gemm (f32, causal block-skip) -> column stats (softmax over axis=1!)
//   -> PV gemm with fused P = exp(s-m_j)/Z_j in A-staging, causal K-truncation.

typedef __attribute__((ext_vector_type(8))) _Float16 half8;
typedef __attribute__((ext_vector_type(4))) float f32x4;
typedef __attribute__((ext_vector_type(8))) unsigned short ushort8;

__device__ __forceinline__ ushort f2h(float f) {
  _Float16 h = (_Float16)f;
  union { _Float16 h; ushort u; } v; v.h = h; return v.u;
}

// ---------------- convert / transpose kernels ----------------
__global__ void k_cvt_x(const float* __restrict__ x, ushort* __restrict__ xh) {
  int i = (blockIdx.x * 256 + threadIdx.x) * 4;
  float4 v = *(const float4*)(x + i);
  ushort4 o;
  o.x = f2h(v.x); o.y = f2h(v.y); o.z = f2h(v.z); o.w = f2h(v.w);
  *(ushort4*)(xh + i) = o;
}

__global__ void k_cvt_w(const float* __restrict__ Wq, const float* __restrict__ Wk,
                        const float* __restrict__ Wv, ushort* __restrict__ Wt) {
  __shared__ ushort tile[32][33];
  const float* W = blockIdx.z == 0 ? Wq : blockIdx.z == 1 ? Wk : Wv;
  int e0 = blockIdx.x * 32, d0 = blockIdx.y * 32;
  for (int r = threadIdx.y; r < 32; r += 8)
    tile[r][threadIdx.x] = f2h(W[(size_t)(d0 + r) * 1024 + e0 + threadIdx.x]);
  __syncthreads();
  ushort* out = Wt + (size_t)blockIdx.z * 1024 * 1024;
  for (int r = threadIdx.y; r < 32; r += 8)
    out[(size_t)(e0 + r) * 1024 + d0 + threadIdx.x] = tile[threadIdx.x][r];
}

// V f16 [b*2048+j][e] -> Vt [b][e][j]
__global__ void k_tr_v(const ushort* __restrict__ V, ushort* __restrict__ Vt) {
  __shared__ ushort tile[32][33];
  int b = blockIdx.z;
  int e0 = blockIdx.x * 32, j0 = blockIdx.y * 32;
  const ushort* src = V + (size_t)b * 2048 * 1024;
  for (int r = threadIdx.y; r < 32; r += 8)
    tile[r][threadIdx.x] = src[(size_t)(j0 + r) * 1024 + e0 + threadIdx.x];
  __syncthreads();
  ushort* dst = Vt + (size_t)b * 1024 * 2048;
  for (int r = threadIdx.y; r < 32; r += 8)
    dst[(size_t)(e0 + r) * 2048 + j0 + threadIdx.x] = tile[threadIdx.x][r];
}

// ---------------- GEMM core (m97-style, 128x128xBK64, 4 waves) ----------------
__device__ __forceinline__ void gload_lds16(const ushort* g, ushort* l) {
  __builtin_amdgcn_global_load_lds(
      (const __attribute__((address_space(1))) void*)g,
      (__attribute__((address_space(3))) void*)l, 16, 0, 0);
}

// EPI: 0 = QKV split (f16 x3), 1 = scores batched (f32, scale+causal, skip bn>bm)
template <int EPI>
__global__ __launch_bounds__(256)
void k_gemm(const ushort* __restrict__ A, const ushort* __restrict__ Bt,
            int K, int lda, int ldb, void* o0, void* o1, void* o2) {
  int bm = blockIdx.y, bn = blockIdx.x;
  if (EPI == 1 && bn > bm) return;   // fully-masked causal tile
  if (EPI == 1) {
    size_t boff = (size_t)blockIdx.z * 2048 * 1024;
    A += boff; Bt += boff;
  }
  __shared__ __align__(16) ushort As[128 * 64];
  __shared__ __align__(16) ushort Bs[128 * 64];
  int t = threadIdx.x;
  int lane = t & 63, wave = t >> 6;
  int wm = (wave >> 1) * 64, wn = (wave & 1) * 64;
  f32x4 acc[4][4] = {};

  int r0 = t >> 3, c0 = (t & 7) * 8;
  const int nk = K >> 6;
  for (int kt = 0; kt < nk; ++kt) {
    const ushort* ga = A + (size_t)(bm * 128) * lda + kt * 64;
    const ushort* gb = Bt + (size_t)(bn * 128) * ldb + kt * 64;
#pragma unroll
    for (int it = 0; it < 4; ++it) {
      int r = it * 32 + r0;
      gload_lds16(ga + (size_t)r * lda + c0, &As[(it * 256 + t) * 8]);
      gload_lds16(gb + (size_t)r * ldb + c0, &Bs[(it * 256 + t) * 8]);
    }
    __syncthreads();
#pragma unroll
    for (int kk = 0; kk < 2; ++kk) {
      half8 af[4], bf[4];
#pragma unroll
      for (int i = 0; i < 4; ++i) {
        af[i] = *(const half8*)&As[(wm + i * 16 + (lane & 15)) * 64 + kk * 32 + (lane >> 4) * 8];
        bf[i] = *(const half8*)&Bs[(wn + i * 16 + (lane & 15)) * 64 + kk * 32 + (lane >> 4) * 8];
      }
#pragma unroll
      for (int i = 0; i < 4; ++i)
#pragma unroll
        for (int j = 0; j < 4; ++j)
          acc[i][j] = __builtin_amdgcn_mfma_f32_16x16x32_f16(af[i], bf[j], acc[i][j], 0, 0, 0);
    }
    __syncthreads();
  }

  int row0 = bm * 128 + wm + ((lane >> 4) << 2);
  int col0 = bn * 128 + wn + (lane & 15);
  if (EPI == 0) {
    ushort* q = (ushort*)o0; ushort* kk_ = (ushort*)o1; ushort* v = (ushort*)o2;
#pragma unroll
    for (int i = 0; i < 4; ++i)
#pragma unroll
      for (int j = 0; j < 4; ++j) {
        int col = col0 + j * 16;
        ushort* dst = col < 1024 ? q : col < 2048 ? kk_ : v;
        int cn = col & 1023;
#pragma unroll
        for (int r = 0; r < 4; ++r)
          dst[(size_t)(row0 + i * 16 + r) * 1024 + cn] = f2h(acc[i][j][r]);
      }
  } else {
    float* sc = (float*)o0 + (size_t)blockIdx.z * 2048 * 2048;
#pragma unroll
    for (int i = 0; i < 4; ++i)
#pragma unroll
      for (int j = 0; j < 4; ++j) {
        int col = col0 + j * 16;
#pragma unroll
        for (int r = 0; r < 4; ++r) {
          int row = row0 + i * 16 + r;
          float vv = acc[i][j][r] * 0.03125f;   // 1/sqrt(1024)
          if (col > row) vv = -1e30f;           // causal (j > i)
          sc[(size_t)row * 2048 + col] = vv;
        }
      }
  }
}

// ---------------- column softmax stats (softmax over i, per column j) ----------------
// Sc upper-triangle TILES are unwritten (poison) -> predicate by i>=j, skip dead threads.
__global__ void k_stats1(const float* __restrict__ Sc, float* __restrict__ pm,
                         float* __restrict__ pz) {
  int b = blockIdx.z;
  const float* S = Sc + (size_t)b * 4194304;
  int j0 = (blockIdx.x * 256 + threadIdx.x) * 4;
  int i0 = blockIdx.y * 128;
  size_t po = ((size_t)b * 16 + blockIdx.y) * 2048 + j0;
  if (i0 + 127 < j0) {           // whole column-chunk masked: never touch (poison) memory
    f32x4 mneg = {-1e30f, -1e30f, -1e30f, -1e30f};
    f32x4 zz = {0.f, 0.f, 0.f, 0.f};
    *(f32x4*)&pm[po] = mneg;
    *(f32x4*)&pz[po] = zz;
    return;
  }
  f32x4 m = {-1e30f, -1e30f, -1e30f, -1e30f};
  f32x4 z = {0.f, 0.f, 0.f, 0.f};
  for (int i = i0; i < i0 + 128; ++i) {
    f32x4 s = *(const f32x4*)&S[(size_t)i * 2048 + j0];
    int d = i - j0;
#pragma unroll
    for (int c = 0; c < 4; ++c) {
      float sv = (d >= c) ? s[c] : -1e30f;   // mask (and poison-guard) j > i
      float nm = fmaxf(m[c], sv);
      z[c] = z[c] * __expf(m[c] - nm) + __expf(sv - nm);
      m[c] = nm;
    }
  }
  *(f32x4*)&pm[po] = m;
  *(f32x4*)&pz[po] = z;
}

__global__ void k_stats2(const float* __restrict__ pm, const float* __restrict__ pz,
                         float* __restrict__ cm, float* __restrict__ cz) {
  int b = blockIdx.z;
  int j = blockIdx.x * 256 + threadIdx.x;
  float m = -1e30f;
#pragma unroll
  for (int c = 0; c < 16; ++c) m = fmaxf(m, pm[((size_t)b * 16 + c) * 2048 + j]);
  float zs = 0.f;
#pragma unroll
  for (int c = 0; c < 16; ++c)
    zs += pz[((size_t)b * 16 + c) * 2048 + j] * __expf(pm[((size_t)b * 16 + c) * 2048 + j] - m);
  cm[(size_t)b * 2048 + j] = m;
  cz[(size_t)b * 2048 + j] = zs > 0.f ? 1.0f / zs : 0.f;
}

// ---------------- PV gemm: A = P (fused exp from Sc), B = Vt; causal K-truncation ----
__global__ __launch_bounds__(256)
void k_pv(const float* __restrict__ Sc, const float* __restrict__ cm,
          const float* __restrict__ cz, const ushort* __restrict__ Vt,
          float* __restrict__ out) {
  int b = blockIdx.z;
  int bm = blockIdx.y, bn = blockIdx.x;
  const float* S = Sc + (size_t)b * 4194304;
  const float* cmb = cm + (size_t)b * 2048;
  const float* czb = cz + (size_t)b * 2048;
  const ushort* Vb = Vt + (size_t)b * 2097152;
  float* ob = out + (size_t)b * 2097152;

  __shared__ __align__(16) ushort As[128 * 64];
  __shared__ __align__(16) ushort Bs[128 * 64];
  int t = threadIdx.x;
  int lane = t & 63, wave = t >> 6;
  int wm = (wave >> 1) * 64, wn = (wave & 1) * 64;
  f32x4 acc[4][4] = {};

  int r0 = t >> 3, c0 = (t & 7) * 8;
  const int nk = 2 * bm + 2;   // P cols nonzero only for j <= 128*bm+127
  for (int kt = 0; kt < nk; ++kt) {
    // B staging: Vt rows = e, cols = j (ldb = 2048), via global_load_lds
    const ushort* gb = Vb + (size_t)(bn * 128) * 2048 + kt * 64;
#pragma unroll
    for (int it = 0; it < 4; ++it) {
      int r = it * 32 + r0;
      gload_lds16(gb + (size_t)r * 2048 + c0, &Bs[(it * 256 + t) * 8]);
    }
    // A staging: fused P = exp(s - m_j) / Z_j, f32 -> f16, reg->LDS
    int j0 = kt * 64 + c0;
    f32x4 m0 = *(const f32x4*)&cmb[j0];
    f32x4 m1 = *(const f32x4*)&cmb[j0 + 4];
    f32x4 z0 = *(const f32x4*)&czb[j0];
    f32x4 z1 = *(const f32x4*)&czb[j0 + 4];
#pragma unroll
    for (int it = 0; it < 4; ++it) {
      int r = it * 32 + r0;
      const float* src = &S[(size_t)(bm * 128 + r) * 2048 + j0];
      f32x4 a = *(const f32x4*)src;
      f32x4 c = *(const f32x4*)(src + 4);
      ushort8 p;
#pragma unroll
      for (int q = 0; q < 4; ++q) p[q] = f2h(__expf(a[q] - m0[q]) * z0[q]);
#pragma unroll
      for (int q = 0; q < 4; ++q) p[4 + q] = f2h(__expf(c[q] - m1[q]) * z1[q]);
      *(ushort8*)&As[r * 64 + c0] = p;
    }
    __syncthreads();
#pragma unroll
    for (int kk = 0; kk < 2; ++kk) {
      half8 af[4], bf[4];
#pragma unroll
      for (int i = 0; i < 4; ++i) {
        af[i] = *(const half8*)&As[(wm + i * 16 + (lane & 15)) * 64 + kk * 32 + (lane >> 4) * 8];
        bf[i] = *(const half8*)&Bs[(wn + i * 16 + (lane & 15)) * 64 + kk * 32 + (lane >> 4) * 8];
      }
#pragma unroll
      for (int i = 0; i < 4; ++i)
#pragma unroll
        for (int j = 0; j < 4; ++j)
          acc[i][j] = __builtin_amdgcn_mfma_f32_16x16x32_f16(af[i], bf[j], acc[i][j], 0, 0, 0);
    }
    __syncthreads();
  }

  int row0 = bm * 128 + wm + ((lane >> 4) << 2);
  int col0 = bn * 128 + wn + (lane & 15);
#pragma unroll
  for (int i = 0; i < 4; ++i)
#pragma unroll
    for (int j = 0; j < 4; ++j) {
      int col = col0 + j * 16;
#pragma unroll
      for (int r = 0; r < 4; ++r)
        ob[(size_t)(row0 + i * 16 + r) * 1024 + col] = acc[i][j][r];
    }
}

// ---------------- host ----------------
extern "C" void kernel_launch(void* const* d_in, const int* in_sizes, int n_in,
                              void* d_out, int out_size, void* d_ws, size_t ws_size,
                              hipStream_t stream) {
  const float* x  = (const float*)d_in[0];
  const float* Wq = (const float*)d_in[1];
  const float* Wk = (const float*)d_in[2];
  const float* Wv = (const float*)d_in[3];
  float* out = (float*)d_out;
  char* ws = (char*)d_ws;

  // ws layout (bytes), peak ~117.4 MB:
  ushort* Qh = (ushort*)(ws);                 // 16,777,216
  ushort* Kh = (ushort*)(ws + 16777216);      // 16,777,216
  ushort* Vt = (ushort*)(ws + 33554432);      // 16,777,216
  float*  Sc = (float*) (ws + 50331648);      // 4 x 2048*2048*4 = 67,108,864
  // transient (dead before Sc is written):
  ushort* xh = (ushort*)(ws + 50331648);      // 16,777,216 (dead after QKV)
  ushort* Wt = (ushort*)(ws + 67108864);      //  6,291,456 (dead after QKV)
  ushort* Vh = (ushort*)(ws + 73400320);      // 16,777,216 (dead after tr_v)
  // stats live after Qh is dead:
  float*  pm = (float*) (ws);                 // 4*16*2048*4 = 524,288
  float*  pz = (float*) (ws + 524288);        // 524,288
  float*  cm = (float*) (ws + 1048576);       // 32,768
  float*  cz = (float*) (ws + 1081344);       // 32,768

  k_cvt_x<<<8192, 256, 0, stream>>>(x, xh);
  k_cvt_w<<<dim3(32, 32, 3), dim3(32, 8), 0, stream>>>(Wq, Wk, Wv, Wt);
  // fused QKV projection: A = xh [8192x1024], Bt = Wt [3072x1024]
  k_gemm<0><<<dim3(24, 64), 256, 0, stream>>>(xh, Wt, 1024, 1024, 1024, Qh, Kh, Vh);
  k_tr_v<<<dim3(32, 64, 4), dim3(32, 8), 0, stream>>>(Vh, Vt);
  // scores, batched over z: C[i][j] = Q_i . K_j
  k_gemm<1><<<dim3(16, 16, 4), 256, 0, stream>>>(Qh, Kh, 1024, 1024, 1024, Sc, nullptr, nullptr);
  k_stats1<<<dim3(2, 16, 4), 256, 0, stream>>>(Sc, pm, pz);
  k_stats2<<<dim3(8, 1, 4), 256, 0, stream>>>(pm, pz, cm, cz);
  // context: A = P(fused) [2048x2048], B = Vt (K truncated per row-block)
  k_pv<<<dim3(8, 16, 4), 256, 0, stream>>>(Sc, cm, cz, Vt, out);
}